// Round 1
// baseline (2929.280 us; speedup 1.0000x reference)
//
#include <hip/hip_runtime.h>

#define UNITS 128
#define IN_DIM 256

// ---------------------------------------------------------------------------
// GEMM: h[node][u] = sum_k x[node][k] * W[k][u]
// block = 256 threads: 8 rows x 32 col-groups (float4 per thread)
// K staged in tiles of 64: Wt = 64x128 fp32 (32 KiB), Xt = 8x64 fp32 (2 KiB)
// ---------------------------------------------------------------------------
__global__ __launch_bounds__(256, 4) void gemm_xw_kernel(
    const float* __restrict__ x, const float* __restrict__ W,
    float* __restrict__ h, int n_nodes) {
  __shared__ float Wt[64 * UNITS];   // 32 KiB, flat [kk][u]
  __shared__ float Xt[8 * 64];       // 2 KiB,  flat [r][kk]

  const int tid = threadIdx.x;
  const int r   = tid >> 5;          // 0..7  row within block
  const int g   = tid & 31;          // 0..31 float4 col group
  const int row0 = blockIdx.x * 8;
  const int row  = row0 + r;

  float4 acc = make_float4(0.f, 0.f, 0.f, 0.f);

  for (int k0 = 0; k0 < IN_DIM; k0 += 64) {
    // --- stage W tile: 64x128 floats contiguous = 2048 float4, 8 per thread
    {
      const float4* Wg = (const float4*)(W + (size_t)k0 * UNITS);
      float4* Ws = (float4*)Wt;
#pragma unroll
      for (int i = 0; i < 8; ++i) {
        Ws[tid + i * 256] = Wg[tid + i * 256];
      }
    }
    // --- stage X tile: 8 rows x 64 floats = 128 float4, first 128 threads
    if (tid < 128) {
      const int xr  = tid >> 4;        // 0..7
      const int xc4 = tid & 15;        // 0..15 float4 within 64 floats
      const int grow = row0 + xr;
      float4 v = make_float4(0.f, 0.f, 0.f, 0.f);
      if (grow < n_nodes) {
        v = ((const float4*)(x + (size_t)grow * IN_DIM + k0))[xc4];
      }
      ((float4*)Xt)[tid] = v;
    }
    __syncthreads();

#pragma unroll 8
    for (int kk = 0; kk < 64; ++kk) {
      const float a = Xt[r * 64 + kk];
      const float4 w = *(const float4*)&Wt[kk * UNITS + g * 4];
      acc.x = fmaf(a, w.x, acc.x);
      acc.y = fmaf(a, w.y, acc.y);
      acc.z = fmaf(a, w.z, acc.z);
      acc.w = fmaf(a, w.w, acc.w);
    }
    __syncthreads();
  }

  if (row < n_nodes) {
    ((float4*)(h + (size_t)row * UNITS))[g] = acc;
  }
}

// ---------------------------------------------------------------------------
// SpMM scatter: one wave (64 lanes) per edge, float2 per lane (128 units)
// out[row] += val * h[col]   via global fp32 atomics
// ---------------------------------------------------------------------------
__global__ __launch_bounds__(256) void spmm_scatter_kernel(
    const int* __restrict__ rows, const int* __restrict__ cols,
    const float* __restrict__ vals, const float* __restrict__ h,
    float* __restrict__ out, int n_edges) {
  const int lane   = threadIdx.x & 63;
  const int wave   = (blockIdx.x * blockDim.x + threadIdx.x) >> 6;
  const int nwaves = (gridDim.x * blockDim.x) >> 6;

  for (int e = wave; e < n_edges; e += nwaves) {
    const int   r = rows[e];
    const int   c = cols[e];
    const float v = vals[e];
    const float2 hv = ((const float2*)(h + (size_t)c * UNITS))[lane];
    float* dst = out + (size_t)r * UNITS + lane * 2;
    atomicAdd(dst + 0, hv.x * v);
    atomicAdd(dst + 1, hv.y * v);
  }
}

// ---------------------------------------------------------------------------
// In-place ReLU, float4 grid-stride
// ---------------------------------------------------------------------------
__global__ __launch_bounds__(256) void relu_kernel(float* __restrict__ out,
                                                   int n4) {
  const int stride = gridDim.x * blockDim.x;
  for (int i = blockIdx.x * blockDim.x + threadIdx.x; i < n4; i += stride) {
    float4 v = ((float4*)out)[i];
    v.x = v.x > 0.f ? v.x : 0.f;
    v.y = v.y > 0.f ? v.y : 0.f;
    v.z = v.z > 0.f ? v.z : 0.f;
    v.w = v.w > 0.f ? v.w : 0.f;
    ((float4*)out)[i] = v;
  }
}

extern "C" void kernel_launch(void* const* d_in, const int* in_sizes, int n_in,
                              void* d_out, int out_size, void* d_ws, size_t ws_size,
                              hipStream_t stream) {
  const float* x     = (const float*)d_in[0];
  const float* W     = (const float*)d_in[1];
  const int*   rows  = (const int*)d_in[2];
  const int*   cols  = (const int*)d_in[3];
  const float* vals  = (const float*)d_in[4];
  float*       out   = (float*)d_out;

  const int n_nodes = in_sizes[0] / IN_DIM;   // 100000
  const int n_edges = in_sizes[2];            // 3200000

  float* h = (float*)d_ws;                    // n_nodes*UNITS fp32 = 51.2 MB

  // zero the atomic accumulation target (harness poisons d_out with 0xAA)
  hipMemsetAsync(d_out, 0, (size_t)out_size * sizeof(float), stream);

  // 1) h = x @ W
  const int gemm_blocks = (n_nodes + 7) / 8;
  gemm_xw_kernel<<<gemm_blocks, 256, 0, stream>>>(x, W, h, n_nodes);

  // 2) out += scatter(val * h[col]) by row
  spmm_scatter_kernel<<<8192, 256, 0, stream>>>(rows, cols, vals, h, out, n_edges);

  // 3) relu in place
  const int n4 = out_size / 4;
  relu_kernel<<<4096, 256, 0, stream>>>(out, n4);
}

// Round 2
// 1144.353 us; speedup vs baseline: 2.5598x; 2.5598x over previous
//
#include <hip/hip_runtime.h>

#define UNITS 128
#define IN_DIM 256

// ---------------------------------------------------------------------------
// GEMM: h[node][u] = sum_k x[node][k] * W[k][u]   (unchanged from R1)
// ---------------------------------------------------------------------------
__global__ __launch_bounds__(256, 4) void gemm_xw_kernel(
    const float* __restrict__ x, const float* __restrict__ W,
    float* __restrict__ h, int n_nodes) {
  __shared__ float Wt[64 * UNITS];
  __shared__ float Xt[8 * 64];

  const int tid = threadIdx.x;
  const int r   = tid >> 5;
  const int g   = tid & 31;
  const int row0 = blockIdx.x * 8;
  const int row  = row0 + r;

  float4 acc = make_float4(0.f, 0.f, 0.f, 0.f);

  for (int k0 = 0; k0 < IN_DIM; k0 += 64) {
    {
      const float4* Wg = (const float4*)(W + (size_t)k0 * UNITS);
      float4* Ws = (float4*)Wt;
#pragma unroll
      for (int i = 0; i < 8; ++i) Ws[tid + i * 256] = Wg[tid + i * 256];
    }
    if (tid < 128) {
      const int xr  = tid >> 4;
      const int xc4 = tid & 15;
      const int grow = row0 + xr;
      float4 v = make_float4(0.f, 0.f, 0.f, 0.f);
      if (grow < n_nodes)
        v = ((const float4*)(x + (size_t)grow * IN_DIM + k0))[xc4];
      ((float4*)Xt)[tid] = v;
    }
    __syncthreads();

#pragma unroll 8
    for (int kk = 0; kk < 64; ++kk) {
      const float a = Xt[r * 64 + kk];
      const float4 w = *(const float4*)&Wt[kk * UNITS + g * 4];
      acc.x = fmaf(a, w.x, acc.x);
      acc.y = fmaf(a, w.y, acc.y);
      acc.z = fmaf(a, w.z, acc.z);
      acc.w = fmaf(a, w.w, acc.w);
    }
    __syncthreads();
  }

  if (row < n_nodes) ((float4*)(h + (size_t)row * UNITS))[g] = acc;
}

// ---------------------------------------------------------------------------
// CSR build step 1: histogram of rows
// ---------------------------------------------------------------------------
__global__ __launch_bounds__(256) void hist_kernel(
    const int* __restrict__ rows, int* __restrict__ cnt, int n_edges) {
  const int stride = gridDim.x * blockDim.x;
  for (int e = blockIdx.x * blockDim.x + threadIdx.x; e < n_edges; e += stride)
    atomicAdd(&cnt[rows[e]], 1);
}

// ---------------------------------------------------------------------------
// CSR build step 2: exclusive scan over n counters (single workgroup, 1024 thr)
// writes row_start[0..n] and cursor[0..n-1] (= row_start copy for scatter)
// ---------------------------------------------------------------------------
__global__ __launch_bounds__(1024) void scan_kernel(
    const int* __restrict__ cnt, int* __restrict__ row_start,
    int* __restrict__ cursor, int n) {
  __shared__ int sdata[1024];
  const int t = threadIdx.x;
  const int chunk = (n + 1023) >> 10;
  const int base = t * chunk;

  int s = 0;
  for (int i = 0; i < chunk; ++i) {
    const int idx = base + i;
    if (idx < n) s += cnt[idx];
  }
  sdata[t] = s;
  __syncthreads();

  for (int off = 1; off < 1024; off <<= 1) {
    int v = 0;
    if (t >= off) v = sdata[t - off];
    __syncthreads();
    if (t >= off) sdata[t] += v;
    __syncthreads();
  }

  int run = (t > 0) ? sdata[t - 1] : 0;
  for (int i = 0; i < chunk; ++i) {
    const int idx = base + i;
    if (idx < n) {
      row_start[idx] = run;
      cursor[idx]    = run;
      run += cnt[idx];
    }
  }
  if (t == 1023) row_start[n] = sdata[1023];
}

// ---------------------------------------------------------------------------
// CSR build step 3: scatter edges into row-sorted order
// ---------------------------------------------------------------------------
__global__ __launch_bounds__(256) void scatter_kernel(
    const int* __restrict__ rows, const int* __restrict__ cols,
    const float* __restrict__ vals, int* __restrict__ cursor,
    int* __restrict__ scol, float* __restrict__ sval, int n_edges) {
  const int stride = gridDim.x * blockDim.x;
  for (int e = blockIdx.x * blockDim.x + threadIdx.x; e < n_edges; e += stride) {
    const int r = rows[e];
    const int pos = atomicAdd(&cursor[r], 1);
    scol[pos] = cols[e];
    sval[pos] = vals[e];
  }
}

// ---------------------------------------------------------------------------
// Aggregate: one wave per row. Gather h[col] (float2/lane), register-accumulate,
// fused relu, single store. No atomics.
// ---------------------------------------------------------------------------
__global__ __launch_bounds__(256) void aggregate_kernel(
    const int* __restrict__ row_start, const int* __restrict__ scol,
    const float* __restrict__ sval, const float* __restrict__ h,
    float* __restrict__ out, int n_rows) {
  const int lane = threadIdx.x & 63;
  const int row  = (blockIdx.x * blockDim.x + threadIdx.x) >> 6;
  if (row >= n_rows) return;

  const int e0 = row_start[row];
  const int e1 = row_start[row + 1];

  float accx = 0.f, accy = 0.f;

  for (int base = e0; base < e1; base += 64) {
    const int m = min(64, e1 - base);
    int   c = 0;
    float v = 0.f;
    if (lane < m) {
      c = scol[base + lane];
      v = sval[base + lane];
    }
    for (int j = 0; j < m; ++j) {
      const int   cj = __shfl(c, j);
      const float vj = __shfl(v, j);
      const float2 hv = ((const float2*)(h + (size_t)cj * UNITS))[lane];
      accx = fmaf(vj, hv.x, accx);
      accy = fmaf(vj, hv.y, accy);
    }
  }

  float2 o;
  o.x = accx > 0.f ? accx : 0.f;
  o.y = accy > 0.f ? accy : 0.f;
  ((float2*)(out + (size_t)row * UNITS))[lane] = o;
}

// ---------------------------------------------------------------------------
extern "C" void kernel_launch(void* const* d_in, const int* in_sizes, int n_in,
                              void* d_out, int out_size, void* d_ws, size_t ws_size,
                              hipStream_t stream) {
  const float* x     = (const float*)d_in[0];
  const float* W     = (const float*)d_in[1];
  const int*   rows  = (const int*)d_in[2];
  const int*   cols  = (const int*)d_in[3];
  const float* vals  = (const float*)d_in[4];
  float*       out   = (float*)d_out;

  const int n_nodes = in_sizes[0] / IN_DIM;   // 100000
  const int n_edges = in_sizes[2];            // 3200000

  // workspace layout (512B-aligned slices)
  char* ws = (char*)d_ws;
  size_t off = 0;
  auto alloc = [&](size_t bytes) {
    char* p = ws + off;
    off += (bytes + 511) & ~(size_t)511;
    return p;
  };
  float* h         = (float*)alloc((size_t)n_nodes * UNITS * sizeof(float)); // 51.2MB
  int*   cnt       = (int*)  alloc((size_t)n_nodes * sizeof(int));
  int*   row_start = (int*)  alloc((size_t)(n_nodes + 1) * sizeof(int));
  int*   cursor    = (int*)  alloc((size_t)n_nodes * sizeof(int));
  int*   scol      = (int*)  alloc((size_t)n_edges * sizeof(int));           // 12.8MB
  float* sval      = (float*)alloc((size_t)n_edges * sizeof(float));         // 12.8MB

  // 1) h = x @ W
  gemm_xw_kernel<<<(n_nodes + 7) / 8, 256, 0, stream>>>(x, W, h, n_nodes);

  // 2) CSR build
  hipMemsetAsync(cnt, 0, (size_t)n_nodes * sizeof(int), stream);
  hist_kernel<<<2048, 256, 0, stream>>>(rows, cnt, n_edges);
  scan_kernel<<<1, 1024, 0, stream>>>(cnt, row_start, cursor, n_nodes);
  scatter_kernel<<<2048, 256, 0, stream>>>(rows, cols, vals, cursor, scol, sval, n_edges);

  // 3) aggregate + relu (one wave per row, no atomics)
  aggregate_kernel<<<(n_nodes * 64 + 255) / 256, 256, 0, stream>>>(
      row_start, scol, sval, h, out, n_nodes);
}

// Round 3
// 849.429 us; speedup vs baseline: 3.4485x; 1.3472x over previous
//
#include <hip/hip_runtime.h>

#define UNITS 128
#define IN_DIM 256
#define BK 32

// ---------------------------------------------------------------------------
// GEMM: h = x @ W.  Block tile 64 rows x 128 cols, BK=32.
// Per thread: 8 rows x 4 cols (32 acc). Per kk: 3x ds_read_b128 + 32 FMA.
// ---------------------------------------------------------------------------
__global__ __launch_bounds__(256) void gemm_xw_kernel(
    const float* __restrict__ x, const float* __restrict__ W,
    float* __restrict__ h, int n_nodes) {
  __shared__ float Wt[BK * UNITS];   // 16 KiB  [kk][u]
  __shared__ float Xt[BK * 64];      // 8 KiB   [kk][r]  (transposed)

  const int tid = threadIdx.x;
  const int g   = tid & 31;          // col group (4 cols)
  const int tr  = tid >> 5;          // 0..7 (8 rows each)
  const int row0 = blockIdx.x * 64;

  float4 acc[8];
#pragma unroll
  for (int i = 0; i < 8; ++i) acc[i] = make_float4(0.f, 0.f, 0.f, 0.f);

  const int sr = tid & 63;           // staging row 0..63
  const int cg = tid >> 6;           // 0..3
  const int grow = row0 + sr;

  for (int k0 = 0; k0 < IN_DIM; k0 += BK) {
    // stage W tile: BK x 128 = 1024 float4, 4 per thread (coalesced)
    {
      const float4* Wg = (const float4*)(W + (size_t)k0 * UNITS);
      float4* Ws = (float4*)Wt;
#pragma unroll
      for (int i = 0; i < 4; ++i) Ws[tid + i * 256] = Wg[tid + i * 256];
    }
    // stage X tile transposed: 64 rows x BK -> Xt[kk][r]
#pragma unroll
    for (int i = 0; i < 2; ++i) {
      const int c4 = cg + i * 4;     // 0..7 (float4 index within BK)
      float4 v = make_float4(0.f, 0.f, 0.f, 0.f);
      if (grow < n_nodes)
        v = *(const float4*)(x + (size_t)grow * IN_DIM + k0 + c4 * 4);
      Xt[(c4 * 4 + 0) * 64 + sr] = v.x;
      Xt[(c4 * 4 + 1) * 64 + sr] = v.y;
      Xt[(c4 * 4 + 2) * 64 + sr] = v.z;
      Xt[(c4 * 4 + 3) * 64 + sr] = v.w;
    }
    __syncthreads();

#pragma unroll 8
    for (int kk = 0; kk < BK; ++kk) {
      const float4 w  = ((const float4*)Wt)[kk * 32 + g];
      const float4 a0 = ((const float4*)Xt)[kk * 16 + tr * 2];
      const float4 a1 = ((const float4*)Xt)[kk * 16 + tr * 2 + 1];
      acc[0].x = fmaf(a0.x, w.x, acc[0].x); acc[0].y = fmaf(a0.x, w.y, acc[0].y);
      acc[0].z = fmaf(a0.x, w.z, acc[0].z); acc[0].w = fmaf(a0.x, w.w, acc[0].w);
      acc[1].x = fmaf(a0.y, w.x, acc[1].x); acc[1].y = fmaf(a0.y, w.y, acc[1].y);
      acc[1].z = fmaf(a0.y, w.z, acc[1].z); acc[1].w = fmaf(a0.y, w.w, acc[1].w);
      acc[2].x = fmaf(a0.z, w.x, acc[2].x); acc[2].y = fmaf(a0.z, w.y, acc[2].y);
      acc[2].z = fmaf(a0.z, w.z, acc[2].z); acc[2].w = fmaf(a0.z, w.w, acc[2].w);
      acc[3].x = fmaf(a0.w, w.x, acc[3].x); acc[3].y = fmaf(a0.w, w.y, acc[3].y);
      acc[3].z = fmaf(a0.w, w.z, acc[3].z); acc[3].w = fmaf(a0.w, w.w, acc[3].w);
      acc[4].x = fmaf(a1.x, w.x, acc[4].x); acc[4].y = fmaf(a1.x, w.y, acc[4].y);
      acc[4].z = fmaf(a1.x, w.z, acc[4].z); acc[4].w = fmaf(a1.x, w.w, acc[4].w);
      acc[5].x = fmaf(a1.y, w.x, acc[5].x); acc[5].y = fmaf(a1.y, w.y, acc[5].y);
      acc[5].z = fmaf(a1.y, w.z, acc[5].z); acc[5].w = fmaf(a1.y, w.w, acc[5].w);
      acc[6].x = fmaf(a1.z, w.x, acc[6].x); acc[6].y = fmaf(a1.z, w.y, acc[6].y);
      acc[6].z = fmaf(a1.z, w.z, acc[6].z); acc[6].w = fmaf(a1.z, w.w, acc[6].w);
      acc[7].x = fmaf(a1.w, w.x, acc[7].x); acc[7].y = fmaf(a1.w, w.y, acc[7].y);
      acc[7].z = fmaf(a1.w, w.z, acc[7].z); acc[7].w = fmaf(a1.w, w.w, acc[7].w);
    }
    __syncthreads();
  }

#pragma unroll
  for (int i = 0; i < 8; ++i) {
    const int rr = row0 + tr * 8 + i;
    if (rr < n_nodes)
      ((float4*)(h + (size_t)rr * UNITS))[g] = acc[i];
  }
}

// ---------------------------------------------------------------------------
// CSR build step 1: histogram of rows
// ---------------------------------------------------------------------------
__global__ __launch_bounds__(256) void hist_kernel(
    const int* __restrict__ rows, int* __restrict__ cnt, int n_edges) {
  const int stride = gridDim.x * blockDim.x;
  for (int e = blockIdx.x * blockDim.x + threadIdx.x; e < n_edges; e += stride)
    atomicAdd(&cnt[rows[e]], 1);
}

// ---------------------------------------------------------------------------
// Hierarchical exclusive scan (3 tiny kernels)
// ---------------------------------------------------------------------------
__global__ __launch_bounds__(256) void scan_reduce_kernel(
    const int* __restrict__ cnt, int* __restrict__ bsum, int n) {
  __shared__ int s[256];
  const int t = threadIdx.x;
  const int idx = blockIdx.x * 256 + t;
  s[t] = (idx < n) ? cnt[idx] : 0;
  __syncthreads();
  for (int off = 128; off > 0; off >>= 1) {
    if (t < off) s[t] += s[t + off];
    __syncthreads();
  }
  if (t == 0) bsum[blockIdx.x] = s[0];
}

__global__ __launch_bounds__(512) void scan_bsum_kernel(
    const int* __restrict__ bsum, int* __restrict__ boff, int nb,
    int* __restrict__ row_start, int n) {
  __shared__ int s[512];
  const int t = threadIdx.x;
  const int v = (t < nb) ? bsum[t] : 0;
  s[t] = v;
  __syncthreads();
  for (int off = 1; off < 512; off <<= 1) {
    int u = 0;
    if (t >= off) u = s[t - off];
    __syncthreads();
    if (t >= off) s[t] += u;
    __syncthreads();
  }
  if (t < nb) boff[t] = s[t] - v;            // exclusive prefix
  if (t == 511) row_start[n] = s[511];       // grand total
}

__global__ __launch_bounds__(256) void scan_final_kernel(
    const int* __restrict__ cnt, const int* __restrict__ boff,
    int* __restrict__ row_start, int* __restrict__ cursor, int n) {
  __shared__ int s[256];
  const int t = threadIdx.x;
  const int idx = blockIdx.x * 256 + t;
  const int v = (idx < n) ? cnt[idx] : 0;
  s[t] = v;
  __syncthreads();
  for (int off = 1; off < 256; off <<= 1) {
    int u = 0;
    if (t >= off) u = s[t - off];
    __syncthreads();
    if (t >= off) s[t] += u;
    __syncthreads();
  }
  const int excl = boff[blockIdx.x] + s[t] - v;
  if (idx < n) {
    row_start[idx] = excl;
    cursor[idx]    = excl;
  }
}

// ---------------------------------------------------------------------------
// CSR build step 3: scatter edges as paired (col, valbits) 8B stores
// ---------------------------------------------------------------------------
__global__ __launch_bounds__(256) void scatter_kernel(
    const int* __restrict__ rows, const int* __restrict__ cols,
    const float* __restrict__ vals, int* __restrict__ cursor,
    int2* __restrict__ spair, int n_edges) {
  const int stride = gridDim.x * blockDim.x;
  for (int e = blockIdx.x * blockDim.x + threadIdx.x; e < n_edges; e += stride) {
    const int r = rows[e];
    const int pos = atomicAdd(&cursor[r], 1);
    spair[pos] = make_int2(cols[e], __float_as_int(vals[e]));
  }
}

// ---------------------------------------------------------------------------
// Aggregate: one wave per row, register accumulate, fused relu, no atomics
// ---------------------------------------------------------------------------
__global__ __launch_bounds__(256) void aggregate_kernel(
    const int* __restrict__ row_start, const int2* __restrict__ spair,
    const float* __restrict__ h, float* __restrict__ out, int n_rows) {
  const int lane = threadIdx.x & 63;
  const int row  = (blockIdx.x * blockDim.x + threadIdx.x) >> 6;
  if (row >= n_rows) return;

  const int e0 = row_start[row];
  const int e1 = row_start[row + 1];

  float accx = 0.f, accy = 0.f;

  for (int base = e0; base < e1; base += 64) {
    const int m = min(64, e1 - base);
    int2 p = make_int2(0, 0);
    if (lane < m) p = spair[base + lane];
    for (int j = 0; j < m; ++j) {
      const int   cj = __shfl(p.x, j);
      const float vj = __int_as_float(__shfl(p.y, j));
      const float2 hv = ((const float2*)(h + (size_t)cj * UNITS))[lane];
      accx = fmaf(vj, hv.x, accx);
      accy = fmaf(vj, hv.y, accy);
    }
  }

  float2 o;
  o.x = accx > 0.f ? accx : 0.f;
  o.y = accy > 0.f ? accy : 0.f;
  ((float2*)(out + (size_t)row * UNITS))[lane] = o;
}

// ---------------------------------------------------------------------------
extern "C" void kernel_launch(void* const* d_in, const int* in_sizes, int n_in,
                              void* d_out, int out_size, void* d_ws, size_t ws_size,
                              hipStream_t stream) {
  const float* x     = (const float*)d_in[0];
  const float* W     = (const float*)d_in[1];
  const int*   rows  = (const int*)d_in[2];
  const int*   cols  = (const int*)d_in[3];
  const float* vals  = (const float*)d_in[4];
  float*       out   = (float*)d_out;

  const int n_nodes = in_sizes[0] / IN_DIM;   // 100000
  const int n_edges = in_sizes[2];            // 3200000

  char* ws = (char*)d_ws;
  size_t off = 0;
  auto alloc = [&](size_t bytes) {
    char* p = ws + off;
    off += (bytes + 511) & ~(size_t)511;
    return p;
  };
  float* h         = (float*)alloc((size_t)n_nodes * UNITS * sizeof(float)); // 51.2MB
  int*   cnt       = (int*)  alloc((size_t)n_nodes * sizeof(int));
  int*   row_start = (int*)  alloc((size_t)(n_nodes + 1) * sizeof(int));
  int*   cursor    = (int*)  alloc((size_t)n_nodes * sizeof(int));
  int*   bsum      = (int*)  alloc(512 * sizeof(int));
  int*   boff      = (int*)  alloc(512 * sizeof(int));
  int2*  spair     = (int2*) alloc((size_t)n_edges * sizeof(int2));          // 25.6MB

  const int nb = (n_nodes + 255) / 256;       // 391 scan blocks

  // 1) h = x @ W
  gemm_xw_kernel<<<(n_nodes + 63) / 64, 256, 0, stream>>>(x, W, h, n_nodes);

  // 2) CSR build
  hipMemsetAsync(cnt, 0, (size_t)n_nodes * sizeof(int), stream);
  hist_kernel<<<2048, 256, 0, stream>>>(rows, cnt, n_edges);
  scan_reduce_kernel<<<nb, 256, 0, stream>>>(cnt, bsum, n_nodes);
  scan_bsum_kernel<<<1, 512, 0, stream>>>(bsum, boff, nb, row_start, n_nodes);
  scan_final_kernel<<<nb, 256, 0, stream>>>(cnt, boff, row_start, cursor, n_nodes);
  scatter_kernel<<<2048, 256, 0, stream>>>(rows, cols, vals, cursor, spair, n_edges);

  // 3) aggregate + relu
  aggregate_kernel<<<(n_nodes * 64 + 255) / 256, 256, 0, stream>>>(
      row_start, spair, h, out, n_nodes);
}